// Round 7
// baseline (247.003 us; speedup 1.0000x reference)
//
#include <hip/hip_runtime.h>
#include <math.h>

#define BB 32
#define CC 3
#define HH 512
#define WW 512

typedef float vfloat4 __attribute__((ext_vector_type(4)));  // native vector for nontemporal store

// ---------------------------------------------------------------------------
// Kernel 1: 3x3 matrix exponential for 32 matrices (one per thread), double
// precision scaling-and-squaring + Taylor. Writes top 2 rows (6 floats) per
// batch into E.
// ---------------------------------------------------------------------------
__global__ void expm_kernel(const float* __restrict__ theta, float* __restrict__ E) {
    int b = threadIdx.x;
    if (b >= BB) return;

    double A[3][3];
#pragma unroll
    for (int j = 0; j < 2; ++j)
#pragma unroll
        for (int k = 0; k < 3; ++k)
            A[j][k] = (double)theta[b * 6 + j * 3 + k];
    A[2][0] = A[2][1] = A[2][2] = 0.0;

    // inf-norm
    double nrm = 0.0;
#pragma unroll
    for (int i = 0; i < 3; ++i) {
        double r = fabs(A[i][0]) + fabs(A[i][1]) + fabs(A[i][2]);
        nrm = fmax(nrm, r);
    }
    int s = 0;
    while (nrm > 0.5) { nrm *= 0.5; ++s; }
    double sc = ldexp(1.0, -s);
#pragma unroll
    for (int i = 0; i < 3; ++i)
#pragma unroll
        for (int k = 0; k < 3; ++k) A[i][k] *= sc;

    // Taylor series: R = sum_{k=0..20} A_scaled^k / k!   (||A|| <= 0.5 -> ~1e-16)
    double R[3][3] = {{1, 0, 0}, {0, 1, 0}, {0, 0, 1}};
    double T[3][3] = {{1, 0, 0}, {0, 1, 0}, {0, 0, 1}};
    for (int k = 1; k <= 20; ++k) {
        double N[3][3];
        double inv = 1.0 / (double)k;
#pragma unroll
        for (int i = 0; i < 3; ++i)
#pragma unroll
            for (int j = 0; j < 3; ++j)
                N[i][j] = (T[i][0] * A[0][j] + T[i][1] * A[1][j] + T[i][2] * A[2][j]) * inv;
#pragma unroll
        for (int i = 0; i < 3; ++i)
#pragma unroll
            for (int j = 0; j < 3; ++j) {
                T[i][j] = N[i][j];
                R[i][j] += N[i][j];
            }
    }
    // undo scaling: square s times
    for (int q = 0; q < s; ++q) {
        double N[3][3];
#pragma unroll
        for (int i = 0; i < 3; ++i)
#pragma unroll
            for (int j = 0; j < 3; ++j)
                N[i][j] = R[i][0] * R[0][j] + R[i][1] * R[1][j] + R[i][2] * R[2][j];
#pragma unroll
        for (int i = 0; i < 3; ++i)
#pragma unroll
            for (int j = 0; j < 3; ++j) R[i][j] = N[i][j];
    }

#pragma unroll
    for (int j = 0; j < 2; ++j)
#pragma unroll
        for (int k = 0; k < 3; ++k)
            E[b * 6 + j * 3 + k] = (float)R[j][k];
}

// ---------------------------------------------------------------------------
// Kernel 2: affine grid + bilinear grid_sample (zeros padding,
// align_corners=False). One thread handles 4 consecutive w pixels for all 3
// channels -> 16B nontemporal stores per channel (output is write-once;
// keep L2/L3 for the gather-reused input).
// total threads = B * H * (W/4) = 32*512*128 = 2,097,152 -> 8192 blocks x 256
// Each batch b spans 256 consecutive blocks, so b = blockIdx.x >> 8 is
// wave-uniform -> theta coefficients load via the scalar path.
// ---------------------------------------------------------------------------
__global__ __launch_bounds__(256) void st_sample_kernel(const float* __restrict__ x,
                                                        const float* __restrict__ E,
                                                        float* __restrict__ out) {
    const int b = blockIdx.x >> 8;                    // uniform per block
    const int tid_in_b = (blockIdx.x & 255) * 256 + threadIdx.x;  // 0..65535
    const int wq = tid_in_b & (WW / 4 - 1);
    const int h = tid_in_b >> 7;

    const float t00 = E[b * 6 + 0], t01 = E[b * 6 + 1], t02 = E[b * 6 + 2];
    const float t10 = E[b * 6 + 3], t11 = E[b * 6 + 4], t12 = E[b * 6 + 5];

    const float gy = (2.0f * (float)h + 1.0f) * (1.0f / (float)HH) - 1.0f;
    const float* __restrict__ xb = x + (size_t)b * CC * HH * WW;

    float acc[CC][4];

#pragma unroll
    for (int j = 0; j < 4; ++j) {
        int w = wq * 4 + j;
        float gx = (2.0f * (float)w + 1.0f) * (1.0f / (float)WW) - 1.0f;
        // grid = theta * [gx, gy, 1]
        float grid_x = t00 * gx + t01 * gy + t02;
        float grid_y = t10 * gx + t11 * gy + t12;
        // unnormalize (align_corners=False)
        float ix = (grid_x + 1.0f) * ((float)WW * 0.5f) - 0.5f;
        float iy = (grid_y + 1.0f) * ((float)HH * 0.5f) - 0.5f;

        bool any = (ix > -1.0f) & (ix < (float)WW) & (iy > -1.0f) & (iy < (float)HH);
        if (any) {
            float x0f = floorf(ix), y0f = floorf(iy);
            float x1f = x0f + 1.0f, y1f = y0f + 1.0f;
            float wa = (x1f - ix) * (y1f - iy);  // (x0,y0)
            float wb = (x1f - ix) * (iy - y0f);  // (x0,y1)
            float wc = (ix - x0f) * (y1f - iy);  // (x1,y0)
            float wd = (ix - x0f) * (iy - y0f);  // (x1,y1)

            float mx0 = (x0f >= 0.0f) ? 1.0f : 0.0f;             // x0 <= W-1 implied by ix < W
            float mx1 = (x1f <= (float)(WW - 1)) ? 1.0f : 0.0f;  // x1 >= 0 implied by ix > -1
            float my0 = (y0f >= 0.0f) ? 1.0f : 0.0f;
            float my1 = (y1f <= (float)(HH - 1)) ? 1.0f : 0.0f;

            int xi0 = (int)fminf(fmaxf(x0f, 0.0f), (float)(WW - 1));
            int xi1 = (int)fminf(fmaxf(x1f, 0.0f), (float)(WW - 1));
            int yi0 = (int)fminf(fmaxf(y0f, 0.0f), (float)(HH - 1));
            int yi1 = (int)fminf(fmaxf(y1f, 0.0f), (float)(HH - 1));

            float wA = wa * mx0 * my0;
            float wB = wb * mx0 * my1;
            float wC = wc * mx1 * my0;
            float wD = wd * mx1 * my1;

            int o00 = yi0 * WW + xi0;
            int o01 = yi1 * WW + xi0;
            int o10 = yi0 * WW + xi1;
            int o11 = yi1 * WW + xi1;

#pragma unroll
            for (int c = 0; c < CC; ++c) {
                const float* __restrict__ xc = xb + c * (HH * WW);
                acc[c][j] = wA * xc[o00] + wB * xc[o01] + wC * xc[o10] + wD * xc[o11];
            }
        } else {
#pragma unroll
            for (int c = 0; c < CC; ++c) acc[c][j] = 0.0f;
        }
    }

    size_t obase = ((size_t)b * CC) * (HH * WW) + (size_t)h * WW + (size_t)wq * 4;
#pragma unroll
    for (int c = 0; c < CC; ++c) {
        vfloat4 v = {acc[c][0], acc[c][1], acc[c][2], acc[c][3]};
        __builtin_nontemporal_store(v, reinterpret_cast<vfloat4*>(out + obase + (size_t)c * (HH * WW)));
    }
}

extern "C" void kernel_launch(void* const* d_in, const int* in_sizes, int n_in,
                              void* d_out, int out_size, void* d_ws, size_t ws_size,
                              hipStream_t stream) {
    const float* x = (const float*)d_in[0];
    const float* theta = (const float*)d_in[1];
    float* out = (float*)d_out;
    float* E = (float*)d_ws;  // 32*6 floats

    expm_kernel<<<1, 64, 0, stream>>>(theta, E);

    const int total = BB * HH * (WW / 4);  // 2,097,152 threads
    st_sample_kernel<<<total / 256, 256, 0, stream>>>(x, E, out);
}

// Round 8
// 217.948 us; speedup vs baseline: 1.1333x; 1.1333x over previous
//
#include <hip/hip_runtime.h>
#include <math.h>

#define BB 32
#define CC 3
#define HH 512
#define WW 512

typedef float vfloat4 __attribute__((ext_vector_type(4)));  // native vector for nontemporal store

// 8-byte load at 4-byte alignment (CDNA supports unaligned multi-dword global
// loads; memcpy lets clang emit global_load_dwordx2 with align 4).
struct f2 { float a, b; };
__device__ __forceinline__ f2 load_f2(const float* __restrict__ p) {
    f2 r;
    __builtin_memcpy(&r, p, sizeof(f2));
    return r;
}

// ---------------------------------------------------------------------------
// Kernel 1: 3x3 matrix exponential, one matrix per thread, double precision
// scaling-and-squaring + fully-unrolled 14-term Taylor (1/k folds to
// compile-time constants -> no f64 divides). ||A_scaled||<=0.5 -> err ~7e-16.
// ---------------------------------------------------------------------------
__global__ void expm_kernel(const float* __restrict__ theta, float* __restrict__ E) {
    int b = threadIdx.x;
    if (b >= BB) return;

    double A[3][3];
#pragma unroll
    for (int j = 0; j < 2; ++j)
#pragma unroll
        for (int k = 0; k < 3; ++k)
            A[j][k] = (double)theta[b * 6 + j * 3 + k];
    A[2][0] = A[2][1] = A[2][2] = 0.0;

    double nrm = 0.0;
#pragma unroll
    for (int i = 0; i < 3; ++i) {
        double r = fabs(A[i][0]) + fabs(A[i][1]) + fabs(A[i][2]);
        nrm = fmax(nrm, r);
    }
    int s = 0;
    while (nrm > 0.5) { nrm *= 0.5; ++s; }
    double sc = ldexp(1.0, -s);
#pragma unroll
    for (int i = 0; i < 3; ++i)
#pragma unroll
        for (int k = 0; k < 3; ++k) A[i][k] *= sc;

    double R[3][3] = {{1, 0, 0}, {0, 1, 0}, {0, 0, 1}};
    double T[3][3] = {{1, 0, 0}, {0, 1, 0}, {0, 0, 1}};
#pragma unroll
    for (int k = 1; k <= 14; ++k) {
        double N[3][3];
        const double inv = 1.0 / (double)k;  // compile-time constant (unrolled)
#pragma unroll
        for (int i = 0; i < 3; ++i)
#pragma unroll
            for (int j = 0; j < 3; ++j)
                N[i][j] = (T[i][0] * A[0][j] + T[i][1] * A[1][j] + T[i][2] * A[2][j]) * inv;
#pragma unroll
        for (int i = 0; i < 3; ++i)
#pragma unroll
            for (int j = 0; j < 3; ++j) {
                T[i][j] = N[i][j];
                R[i][j] += N[i][j];
            }
    }
    for (int q = 0; q < s; ++q) {
        double N[3][3];
#pragma unroll
        for (int i = 0; i < 3; ++i)
#pragma unroll
            for (int j = 0; j < 3; ++j)
                N[i][j] = R[i][0] * R[0][j] + R[i][1] * R[1][j] + R[i][2] * R[2][j];
#pragma unroll
        for (int i = 0; i < 3; ++i)
#pragma unroll
            for (int j = 0; j < 3; ++j) R[i][j] = N[i][j];
    }

#pragma unroll
    for (int j = 0; j < 2; ++j)
#pragma unroll
        for (int k = 0; k < 3; ++k)
            E[b * 6 + j * 3 + k] = (float)R[j][k];
}

// ---------------------------------------------------------------------------
// Kernel 2: affine grid + bilinear grid_sample (zeros padding,
// align_corners=False). VMEM-instruction-count optimized: the two x-corners
// of each row are fetched with ONE dwordx2 (clamped base + lane select),
// 24 loads/thread instead of 48. Interior waves (__all in-bounds) use a
// branchless batched-load path for MLP; boundary waves take the guarded path.
// ---------------------------------------------------------------------------
__global__ __launch_bounds__(256) void st_sample_kernel(const float* __restrict__ x,
                                                        const float* __restrict__ E,
                                                        float* __restrict__ out) {
    const int b = blockIdx.x >> 8;                               // wave-uniform
    const int tid_in_b = (blockIdx.x & 255) * 256 + threadIdx.x; // 0..65535
    const int wq = tid_in_b & (WW / 4 - 1);
    const int h = tid_in_b >> 7;

    const float t00 = E[b * 6 + 0], t01 = E[b * 6 + 1], t02 = E[b * 6 + 2];
    const float t10 = E[b * 6 + 3], t11 = E[b * 6 + 4], t12 = E[b * 6 + 5];

    const float gy = (2.0f * (float)h + 1.0f) * (1.0f / (float)HH) - 1.0f;
    const float* __restrict__ xb = x + (size_t)b * CC * HH * WW;

    // Per-pixel precomputed state (all statically indexed -> registers)
    float wAa[4], wBa[4], wCa[4], wDa[4];
    int ib0[4], ib1[4], d0a[4], d1a[4];
    int anya[4];

#pragma unroll
    for (int j = 0; j < 4; ++j) {
        int w = wq * 4 + j;
        float gx = (2.0f * (float)w + 1.0f) * (1.0f / (float)WW) - 1.0f;
        float grid_x = t00 * gx + t01 * gy + t02;
        float grid_y = t10 * gx + t11 * gy + t12;
        float ix = (grid_x + 1.0f) * ((float)WW * 0.5f) - 0.5f;
        float iy = (grid_y + 1.0f) * ((float)HH * 0.5f) - 0.5f;

        bool any = (ix > -1.0f) & (ix < (float)WW) & (iy > -1.0f) & (iy < (float)HH);
        anya[j] = (int)any;
        if (any) {
            float x0f = floorf(ix), y0f = floorf(iy);
            float x1f = x0f + 1.0f, y1f = y0f + 1.0f;
            float wa = (x1f - ix) * (y1f - iy);
            float wb = (x1f - ix) * (iy - y0f);
            float wc = (ix - x0f) * (y1f - iy);
            float wd = (ix - x0f) * (iy - y0f);

            float mx0 = (x0f >= 0.0f) ? 1.0f : 0.0f;
            float mx1 = (x1f <= (float)(WW - 1)) ? 1.0f : 0.0f;
            float my0 = (y0f >= 0.0f) ? 1.0f : 0.0f;
            float my1 = (y1f <= (float)(HH - 1)) ? 1.0f : 0.0f;

            int xi0 = (int)fminf(fmaxf(x0f, 0.0f), (float)(WW - 1));
            int xi1 = (int)fminf(fmaxf(x1f, 0.0f), (float)(WW - 1));
            int yi0 = (int)fminf(fmaxf(y0f, 0.0f), (float)(HH - 1));
            int yi1 = (int)fminf(fmaxf(y1f, 0.0f), (float)(HH - 1));

            int bx = min(xi0, WW - 2);   // dwordx2 window [bx, bx+1], always in-row
            d0a[j] = xi0 - bx;           // 0 or 1
            d1a[j] = xi1 - bx;           // 0 or 1
            ib0[j] = yi0 * WW + bx;
            ib1[j] = yi1 * WW + bx;
            wAa[j] = wa * mx0 * my0;
            wBa[j] = wb * mx0 * my1;
            wCa[j] = wc * mx1 * my0;
            wDa[j] = wd * mx1 * my1;
        } else {
            wAa[j] = wBa[j] = wCa[j] = wDa[j] = 0.0f;
            ib0[j] = ib1[j] = 0;
            d0a[j] = d1a[j] = 0;
        }
    }

    float acc[CC][4];

    const bool all4 = anya[0] & anya[1] & anya[2] & anya[3];
    if (__all((int)all4)) {
        // Interior wave: branchless, 8 dwordx2 loads per channel batched.
#pragma unroll
        for (int c = 0; c < CC; ++c) {
            const float* __restrict__ xc = xb + c * (HH * WW);
            f2 r0[4], r1[4];
#pragma unroll
            for (int j = 0; j < 4; ++j) {
                r0[j] = load_f2(xc + ib0[j]);
                r1[j] = load_f2(xc + ib1[j]);
            }
#pragma unroll
            for (int j = 0; j < 4; ++j) {
                float v00 = d0a[j] ? r0[j].b : r0[j].a;  // (x0,y0)
                float v10 = d1a[j] ? r0[j].b : r0[j].a;  // (x1,y0)
                float v01 = d0a[j] ? r1[j].b : r1[j].a;  // (x0,y1)
                float v11 = d1a[j] ? r1[j].b : r1[j].a;  // (x1,y1)
                acc[c][j] = wAa[j] * v00 + wBa[j] * v01 + wCa[j] * v10 + wDa[j] * v11;
            }
        }
    } else {
        // Boundary / OOB wave: per-pixel guard (fully-OOB pixels issue no loads)
#pragma unroll
        for (int j = 0; j < 4; ++j) {
            if (anya[j]) {
#pragma unroll
                for (int c = 0; c < CC; ++c) {
                    const float* __restrict__ xc = xb + c * (HH * WW);
                    f2 r0 = load_f2(xc + ib0[j]);
                    f2 r1 = load_f2(xc + ib1[j]);
                    float v00 = d0a[j] ? r0.b : r0.a;
                    float v10 = d1a[j] ? r0.b : r0.a;
                    float v01 = d0a[j] ? r1.b : r1.a;
                    float v11 = d1a[j] ? r1.b : r1.a;
                    acc[c][j] = wAa[j] * v00 + wBa[j] * v01 + wCa[j] * v10 + wDa[j] * v11;
                }
            } else {
#pragma unroll
                for (int c = 0; c < CC; ++c) acc[c][j] = 0.0f;
            }
        }
    }

    size_t obase = ((size_t)b * CC) * (HH * WW) + (size_t)h * WW + (size_t)wq * 4;
#pragma unroll
    for (int c = 0; c < CC; ++c) {
        vfloat4 v = {acc[c][0], acc[c][1], acc[c][2], acc[c][3]};
        __builtin_nontemporal_store(v, reinterpret_cast<vfloat4*>(out + obase + (size_t)c * (HH * WW)));
    }
}

extern "C" void kernel_launch(void* const* d_in, const int* in_sizes, int n_in,
                              void* d_out, int out_size, void* d_ws, size_t ws_size,
                              hipStream_t stream) {
    const float* x = (const float*)d_in[0];
    const float* theta = (const float*)d_in[1];
    float* out = (float*)d_out;
    float* E = (float*)d_ws;  // 32*6 floats

    expm_kernel<<<1, 64, 0, stream>>>(theta, E);

    const int total = BB * HH * (WW / 4);  // 2,097,152 threads
    st_sample_kernel<<<total / 256, 256, 0, stream>>>(x, E, out);
}

// Round 9
// 209.811 us; speedup vs baseline: 1.1773x; 1.0388x over previous
//
#include <hip/hip_runtime.h>
#include <math.h>

#define BB 32
#define CC 3
#define HH 512
#define WW 512

// 8-byte load at 4-byte alignment (clang emits global_load_dwordx2, align 4).
struct f2 { float a, b; };
__device__ __forceinline__ f2 load_f2(const float* __restrict__ p) {
    f2 r;
    __builtin_memcpy(&r, p, sizeof(f2));
    return r;
}

// ---------------------------------------------------------------------------
// Kernel 1: 3x3 matrix exponential, one matrix per thread, double precision
// scaling-and-squaring + fully-unrolled 14-term Taylor (1/k folds to
// compile-time constants). ||A_scaled||<=0.5 -> err ~7e-16.
// ---------------------------------------------------------------------------
__global__ void expm_kernel(const float* __restrict__ theta, float* __restrict__ E) {
    int b = threadIdx.x;
    if (b >= BB) return;

    double A[3][3];
#pragma unroll
    for (int j = 0; j < 2; ++j)
#pragma unroll
        for (int k = 0; k < 3; ++k)
            A[j][k] = (double)theta[b * 6 + j * 3 + k];
    A[2][0] = A[2][1] = A[2][2] = 0.0;

    double nrm = 0.0;
#pragma unroll
    for (int i = 0; i < 3; ++i) {
        double r = fabs(A[i][0]) + fabs(A[i][1]) + fabs(A[i][2]);
        nrm = fmax(nrm, r);
    }
    int s = 0;
    while (nrm > 0.5) { nrm *= 0.5; ++s; }
    double sc = ldexp(1.0, -s);
#pragma unroll
    for (int i = 0; i < 3; ++i)
#pragma unroll
        for (int k = 0; k < 3; ++k) A[i][k] *= sc;

    double R[3][3] = {{1, 0, 0}, {0, 1, 0}, {0, 0, 1}};
    double T[3][3] = {{1, 0, 0}, {0, 1, 0}, {0, 0, 1}};
#pragma unroll
    for (int k = 1; k <= 14; ++k) {
        double N[3][3];
        const double inv = 1.0 / (double)k;  // compile-time (unrolled)
#pragma unroll
        for (int i = 0; i < 3; ++i)
#pragma unroll
            for (int j = 0; j < 3; ++j)
                N[i][j] = (T[i][0] * A[0][j] + T[i][1] * A[1][j] + T[i][2] * A[2][j]) * inv;
#pragma unroll
        for (int i = 0; i < 3; ++i)
#pragma unroll
            for (int j = 0; j < 3; ++j) {
                T[i][j] = N[i][j];
                R[i][j] += N[i][j];
            }
    }
    for (int q = 0; q < s; ++q) {
        double N[3][3];
#pragma unroll
        for (int i = 0; i < 3; ++i)
#pragma unroll
            for (int j = 0; j < 3; ++j)
                N[i][j] = R[i][0] * R[0][j] + R[i][1] * R[1][j] + R[i][2] * R[2][j];
#pragma unroll
        for (int i = 0; i < 3; ++i)
#pragma unroll
            for (int j = 0; j < 3; ++j) R[i][j] = N[i][j];
    }

#pragma unroll
    for (int j = 0; j < 2; ++j)
#pragma unroll
        for (int k = 0; k < 3; ++k)
            E[b * 6 + j * 3 + k] = (float)R[j][k];
}

// ---------------------------------------------------------------------------
// Kernel 2: affine grid + bilinear grid_sample, 2D-tiled for cache-line
// locality under arbitrary affine maps. 1 thread = 1 pixel x 3 channels.
// Wave = 8x8 pixel quad (lane -> (lane&7, lane>>3)), block = 16x16 tile
// (wave quadrant (wv&1, wv>>1)). A wave's source footprint is a compact
// parallelogram (~10 cache lines) instead of a 256px-wide diagonal line
// (~64 lines) -> ~6x fewer line requests on the gather side.
// Stores are scalar but each 128B output line is fully covered by the block,
// so L2 write-back merges them (NO nontemporal here - that would bypass L2).
// Grid: 32 batches x 32x32 tiles = 32768 blocks x 256 threads.
// ---------------------------------------------------------------------------
__global__ __launch_bounds__(256) void st_sample_kernel(const float* __restrict__ x,
                                                        const float* __restrict__ E,
                                                        float* __restrict__ out) {
    const int bid = blockIdx.x;
    const int b = bid >> 10;            // 1024 tiles per batch -> wave-uniform
    const int t = bid & 1023;
    const int tileY = t >> 5, tileX = t & 31;

    const int tid = threadIdx.x;
    const int wv = tid >> 6, lane = tid & 63;
    const int px = (tileX << 4) + ((wv & 1) << 3) + (lane & 7);
    const int py = (tileY << 4) + ((wv >> 1) << 3) + (lane >> 3);

    const float t00 = E[b * 6 + 0], t01 = E[b * 6 + 1], t02 = E[b * 6 + 2];
    const float t10 = E[b * 6 + 3], t11 = E[b * 6 + 4], t12 = E[b * 6 + 5];

    const float* __restrict__ xb = x + (size_t)b * CC * HH * WW;

    const float gx = (2.0f * (float)px + 1.0f) * (1.0f / (float)WW) - 1.0f;
    const float gy = (2.0f * (float)py + 1.0f) * (1.0f / (float)HH) - 1.0f;
    const float grid_x = t00 * gx + t01 * gy + t02;
    const float grid_y = t10 * gx + t11 * gy + t12;
    const float ix = (grid_x + 1.0f) * ((float)WW * 0.5f) - 0.5f;
    const float iy = (grid_y + 1.0f) * ((float)HH * 0.5f) - 0.5f;

    float acc[CC] = {0.0f, 0.0f, 0.0f};

    const bool any = (ix > -1.0f) & (ix < (float)WW) & (iy > -1.0f) & (iy < (float)HH);
    if (any) {
        float x0f = floorf(ix), y0f = floorf(iy);
        float x1f = x0f + 1.0f, y1f = y0f + 1.0f;
        float wa = (x1f - ix) * (y1f - iy);
        float wb = (x1f - ix) * (iy - y0f);
        float wc = (ix - x0f) * (y1f - iy);
        float wd = (ix - x0f) * (iy - y0f);

        float mx0 = (x0f >= 0.0f) ? 1.0f : 0.0f;
        float mx1 = (x1f <= (float)(WW - 1)) ? 1.0f : 0.0f;
        float my0 = (y0f >= 0.0f) ? 1.0f : 0.0f;
        float my1 = (y1f <= (float)(HH - 1)) ? 1.0f : 0.0f;

        int xi0 = (int)fminf(fmaxf(x0f, 0.0f), (float)(WW - 1));
        int xi1 = (int)fminf(fmaxf(x1f, 0.0f), (float)(WW - 1));
        int yi0 = (int)fminf(fmaxf(y0f, 0.0f), (float)(HH - 1));
        int yi1 = (int)fminf(fmaxf(y1f, 0.0f), (float)(HH - 1));

        int bx = min(xi0, WW - 2);      // dwordx2 window [bx, bx+1], in-row
        int d0 = xi0 - bx;              // 0 or 1
        int d1 = xi1 - bx;              // 0 or 1
        int ib0 = yi0 * WW + bx;
        int ib1 = yi1 * WW + bx;

        float wA = wa * mx0 * my0;
        float wB = wb * mx0 * my1;
        float wC = wc * mx1 * my0;
        float wD = wd * mx1 * my1;

        // Issue all 6 loads back-to-back for MLP, then compute.
        f2 r0[CC], r1[CC];
#pragma unroll
        for (int c = 0; c < CC; ++c) {
            const float* __restrict__ xc = xb + c * (HH * WW);
            r0[c] = load_f2(xc + ib0);
            r1[c] = load_f2(xc + ib1);
        }
#pragma unroll
        for (int c = 0; c < CC; ++c) {
            float v00 = d0 ? r0[c].b : r0[c].a;
            float v10 = d1 ? r0[c].b : r0[c].a;
            float v01 = d0 ? r1[c].b : r1[c].a;
            float v11 = d1 ? r1[c].b : r1[c].a;
            acc[c] = wA * v00 + wB * v01 + wC * v10 + wD * v11;
        }
    }

    const size_t obase = ((size_t)b * CC) * (HH * WW) + (size_t)py * WW + px;
#pragma unroll
    for (int c = 0; c < CC; ++c)
        out[obase + (size_t)c * (HH * WW)] = acc[c];
}

extern "C" void kernel_launch(void* const* d_in, const int* in_sizes, int n_in,
                              void* d_out, int out_size, void* d_ws, size_t ws_size,
                              hipStream_t stream) {
    const float* x = (const float*)d_in[0];
    const float* theta = (const float*)d_in[1];
    float* out = (float*)d_out;
    float* E = (float*)d_ws;  // 32*6 floats

    expm_kernel<<<1, 64, 0, stream>>>(theta, E);

    const int nblocks = BB * 32 * 32;   // 32768 blocks of 256 threads
    st_sample_kernel<<<nblocks, 256, 0, stream>>>(x, E, out);
}